// Round 6
// baseline (34.779 us; speedup 1.0000x reference)
//
#include <hip/hip_runtime.h>
#include <math.h>

// Gauss2DEffect: per-pixel-sigma horizontal Gaussian blur, f32.
// x: [1,3,1024,1024], sigma: [1,1,1024,1024], out: [1,3,1024,1024]
//
// Round 6: r2 structure (PP=4, 7 float4 window loads per channel, no LDS)
// with register pressure cut for occupancy: weights are NOT stored in a
// wt[4][11] array; the q-recurrence (exp(-i^2/2s^2) = q^(i^2)) is replayed
// per channel. Live per-pixel state across channels: q, q2, hs, invn = 16
// regs instead of 48. norm is accumulated during channel 0 only.
// Clamp logic runs under a wave-uniform-skippable branch: interior waves
// (14 of 16 per row) do 7 clean loads off one base with immediate offsets.

#define HH 1024
#define WW 1024
#define CC 3
#define KK 10
#define PP 4

__global__ __launch_bounds__(256, 6) void gauss1d_kernel(
    const float* __restrict__ x,
    const float* __restrict__ sigma,
    float* __restrict__ out)
{
    const int t  = blockIdx.x * blockDim.x + threadIdx.x;
    const int h  = t >> 8;                  // 256 four-pixel segments per row
    const int w0 = (t & 255) * PP;          // multiple of 4
    const int p0 = h * WW + w0;

    // ---- per-pixel sigma-derived constants (kept across channel loop) ----
    const float4 sg = *reinterpret_cast<const float4*>(sigma + p0);
    const float sgs[PP] = {sg.x, sg.y, sg.z, sg.w};
    float qv[PP], q2v[PP], hsv[PP];
    #pragma unroll
    for (int p = 0; p < PP; ++p) {
        const float sig = sgs[p];
        const float inv2s2 = __builtin_amdgcn_rcpf(2.0f * sig * sig);
        hsv[p] = ceilf(2.0f * sig);          // half_step gate
        qv[p]  = __expf(-inv2s2);            // q = exp(-1/(2s^2))
        q2v[p] = qv[p] * qv[p];
    }

    const int  base    = w0 - 12;            // window start col
    const bool needfix = (w0 < 12) || (w0 > WW - 16);   // edge lanes only
    float invn[PP];

    #pragma unroll
    for (int c = 0; c < CC; ++c) {
        const float* __restrict__ rc = x + c * (HH * WW) + h * WW;
        float v[28];                          // cols [w0-12, w0+15]
        if (!needfix) {                       // interior: wave-uniform skip
            const float* __restrict__ bp = rc + base;   // 16B aligned
            #pragma unroll
            for (int k = 0; k < 7; ++k) {
                const float4 lv = *reinterpret_cast<const float4*>(bp + 4 * k);
                v[4*k+0] = lv.x; v[4*k+1] = lv.y;
                v[4*k+2] = lv.z; v[4*k+3] = lv.w;
            }
        } else {                              // edge: clamped base + broadcast fix
            #pragma unroll
            for (int k = 0; k < 7; ++k) {
                const int bk = base + 4 * k;  // bk % 4 == 0
                int bkc = bk < 0 ? 0 : bk;
                bkc = bkc > (WW - 4) ? (WW - 4) : bkc;
                float4 lv = *reinterpret_cast<const float4*>(rc + bkc);
                if (k < 3) {                  // fully-left-clamped: lv.x == rc[0]
                    const bool cl = bk < 0;
                    lv.y = cl ? lv.x : lv.y;
                    lv.z = cl ? lv.x : lv.z;
                    lv.w = cl ? lv.x : lv.w;
                }
                if (k > 3) {                  // fully-right-clamped: lv.w == rc[1023]
                    const bool cr = bk > (WW - 4);
                    lv.x = cr ? lv.w : lv.x;
                    lv.y = cr ? lv.w : lv.y;
                    lv.z = cr ? lv.w : lv.z;
                }
                v[4*k+0] = lv.x; v[4*k+1] = lv.y;
                v[4*k+2] = lv.z; v[4*k+3] = lv.w;
            }
        }

        float4 res;
        float* rp = reinterpret_cast<float*>(&res);
        #pragma unroll
        for (int p = 0; p < PP; ++p) {
            const int o = 12 + p;             // center index in window
            float acc  = v[o];                // center weight == 1
            float wp   = 1.0f;                // gated w_{i-1}
            float tq   = qv[p];               // q^(2i-1)
            float norm = 1.0f;
            #pragma unroll
            for (int i = 1; i <= KK; ++i) {
                float wi = wp * tq;           // q^(i^2) until gated
                tq *= q2v[p];
                wi = ((float)i <= hsv[p]) ? wi : 0.0f;
                acc += wi * (v[o - i] + v[o + i]);
                if (c == 0) norm += 2.0f * wi;
                wp = wi;
            }
            if (c == 0) invn[p] = __builtin_amdgcn_rcpf(norm);  // norm >= 1
            rp[p] = acc * invn[p];
        }
        *reinterpret_cast<float4*>(out + c * (HH * WW) + p0) = res;
    }
}

extern "C" void kernel_launch(void* const* d_in, const int* in_sizes, int n_in,
                              void* d_out, int out_size, void* d_ws, size_t ws_size,
                              hipStream_t stream) {
    const float* x = (const float*)d_in[0];
    const float* sigma = (const float*)d_in[1];
    float* out = (float*)d_out;

    const int n_threads = (HH * WW) / PP;   // 262144
    const int block = 256;
    const int grid = n_threads / block;     // 1024
    gauss1d_kernel<<<grid, block, 0, stream>>>(x, sigma, out);
}

// Round 7
// 17.684 us; speedup vs baseline: 1.9667x; 1.9667x over previous
//
#include <hip/hip_runtime.h>
#include <math.h>

// Gauss2DEffect: per-pixel-sigma horizontal Gaussian blur, f32.
// x: [1,3,1024,1024], sigma: [1,1,1024,1024], out: [1,3,1024,1024]
//
// Round 7: r2 structure with stall fixes, NATURAL register allocation
// (launch_bounds min-waves caps caused catastrophic spills in r4/r6).
//  - Interior fast path (wave-uniform, 14/16 waves): 7 float4 loads per
//    channel off one base pointer, offsets fold into load immediates.
//  - All 3 channel windows (84 floats) loaded up-front -> single s_waitcnt,
//    then ONE fused pass computes the weight recurrence per pixel and
//    applies it to all 3 channel accumulators (no wt[][] store/reload).
//  - Weights: exp(-i^2/2s^2) = q^(i^2) via recurrence, 1 exp per pixel.

#define HH 1024
#define WW 1024
#define CC 3
#define KK 10
#define PP 4

__global__ __launch_bounds__(256) void gauss1d_kernel(
    const float* __restrict__ x,
    const float* __restrict__ sigma,
    float* __restrict__ out)
{
    const int t  = blockIdx.x * blockDim.x + threadIdx.x;
    const int h  = t >> 8;                  // 256 four-pixel segments per row
    const int w0 = (t & 255) * PP;          // multiple of 4
    const int p0 = h * WW + w0;

    // ---- per-pixel sigma-derived constants ----
    const float4 sg = *reinterpret_cast<const float4*>(sigma + p0);
    const float sgs[PP] = {sg.x, sg.y, sg.z, sg.w};
    float qv[PP], q2v[PP], hsv[PP];
    #pragma unroll
    for (int p = 0; p < PP; ++p) {
        const float sig = sgs[p];
        const float inv2s2 = __builtin_amdgcn_rcpf(2.0f * sig * sig);
        hsv[p] = ceilf(2.0f * sig);          // half_step gate
        qv[p]  = __expf(-inv2s2);            // q = exp(-1/(2s^2))
        q2v[p] = qv[p] * qv[p];
    }

    // ---- load all 3 channel windows up-front ----
    const int  base     = w0 - 12;           // window start col
    const bool interior = (w0 >= 12) && (w0 <= WW - 16);
    float v[CC][28];                         // cols [w0-12, w0+15] per channel
    if (interior) {
        #pragma unroll
        for (int c = 0; c < CC; ++c) {
            const float* __restrict__ bp = x + c * (HH * WW) + h * WW + base;
            #pragma unroll
            for (int k = 0; k < 7; ++k) {
                const float4 lv = *reinterpret_cast<const float4*>(bp + 4 * k);
                v[c][4*k+0] = lv.x; v[c][4*k+1] = lv.y;
                v[c][4*k+2] = lv.z; v[c][4*k+3] = lv.w;
            }
        }
    } else {                                  // 2 of 16 waves per block
        #pragma unroll
        for (int c = 0; c < CC; ++c) {
            const float* __restrict__ rc = x + c * (HH * WW) + h * WW;
            #pragma unroll
            for (int k = 0; k < 7; ++k) {
                const int bk = base + 4 * k;  // bk % 4 == 0
                int bkc = bk < 0 ? 0 : bk;
                bkc = bkc > (WW - 4) ? (WW - 4) : bkc;
                float4 lv = *reinterpret_cast<const float4*>(rc + bkc);
                if (k < 3) {                  // fully-left-clamped: lv.x == rc[0]
                    const bool cl = bk < 0;
                    lv.y = cl ? lv.x : lv.y;
                    lv.z = cl ? lv.x : lv.z;
                    lv.w = cl ? lv.x : lv.w;
                }
                if (k > 3) {                  // fully-right-clamped: lv.w == rc[1023]
                    const bool cr = bk > (WW - 4);
                    lv.x = cr ? lv.w : lv.x;
                    lv.y = cr ? lv.w : lv.y;
                    lv.z = cr ? lv.w : lv.z;
                }
                v[c][4*k+0] = lv.x; v[c][4*k+1] = lv.y;
                v[c][4*k+2] = lv.z; v[c][4*k+3] = lv.w;
            }
        }
    }

    // ---- fused weight recurrence + 3-channel accumulation ----
    float acc[CC][PP];
    #pragma unroll
    for (int c = 0; c < CC; ++c)
        #pragma unroll
        for (int p = 0; p < PP; ++p)
            acc[c][p] = v[c][12 + p];         // center tap, weight == 1
    float wsum[PP] = {0.0f, 0.0f, 0.0f, 0.0f};
    float wp[PP]   = {1.0f, 1.0f, 1.0f, 1.0f};
    float tq[PP]   = {qv[0], qv[1], qv[2], qv[3]};
    #pragma unroll
    for (int i = 1; i <= KK; ++i) {
        #pragma unroll
        for (int p = 0; p < PP; ++p) {
            float wi = wp[p] * tq[p];         // q^(i^2) until gated
            tq[p] *= q2v[p];
            wi = ((float)i <= hsv[p]) ? wi : 0.0f;
            wp[p] = wi;
            wsum[p] += wi;
            const int o = 12 + p;
            #pragma unroll
            for (int c = 0; c < CC; ++c)
                acc[c][p] += wi * (v[c][o - i] + v[c][o + i]);
        }
    }

    // ---- normalize + store ----
    float invn[PP];
    #pragma unroll
    for (int p = 0; p < PP; ++p)
        invn[p] = __builtin_amdgcn_rcpf(fmaf(2.0f, wsum[p], 1.0f));  // norm >= 1
    #pragma unroll
    for (int c = 0; c < CC; ++c) {
        float4 res;
        res.x = acc[c][0] * invn[0];
        res.y = acc[c][1] * invn[1];
        res.z = acc[c][2] * invn[2];
        res.w = acc[c][3] * invn[3];
        *reinterpret_cast<float4*>(out + c * (HH * WW) + p0) = res;
    }
}

extern "C" void kernel_launch(void* const* d_in, const int* in_sizes, int n_in,
                              void* d_out, int out_size, void* d_ws, size_t ws_size,
                              hipStream_t stream) {
    const float* x = (const float*)d_in[0];
    const float* sigma = (const float*)d_in[1];
    float* out = (float*)d_out;

    const int n_threads = (HH * WW) / PP;   // 262144
    const int block = 256;
    const int grid = n_threads / block;     // 1024
    gauss1d_kernel<<<grid, block, 0, stream>>>(x, sigma, out);
}

// Round 8
// 11.921 us; speedup vs baseline: 2.9174x; 1.4834x over previous
//
#include <hip/hip_runtime.h>
#include <math.h>

// Gauss2DEffect: per-pixel-sigma horizontal Gaussian blur, f32.
// x: [1,3,1024,1024], sigma: [1,1,1024,1024], out: [1,3,1024,1024]
//
// Round 8 = round 2 (best: 12.09 us) + interior fast path + rotated mapping.
//  - r2 structure untouched: PP=4, per-channel v[28] window, stored
//    wt[4][10], natural register allocation (NO launch_bounds min-waves:
//    that spilled in r4/r6), no LDS (r3 disproved).
//  - w0 = (tid*4 + 12) & 1023 rotates the row mapping so all 6 edge
//    segments land in the LAST wave of each row-block; waves 0-2 take a
//    wave-uniform execz skip of the clamp path.
//  - Interior: 7 float4 loads per channel off one base pointer, offsets
//    fold into load immediates; no clamps, no cndmasks, no edge loads.
//  - Weights: exp(-i^2/2s^2) = q^(i^2) via recurrence, 1 exp per pixel.

#define HH 1024
#define WW 1024
#define CC 3
#define KK 10
#define PP 4

__global__ __launch_bounds__(256) void gauss1d_kernel(
    const float* __restrict__ x,
    const float* __restrict__ sigma,
    float* __restrict__ out)
{
    const int t   = blockIdx.x * blockDim.x + threadIdx.x;
    const int h   = t >> 8;                    // one row per 256 threads
    const int tid = t & 255;
    const int w0  = (tid * PP + 12) & (WW - 1);  // rotated segment mapping
    const int p0  = h * WW + w0;

    // ---- per-pixel weights (taps 1..10, symmetric; center weight == 1) ----
    const float4 sg4 = *reinterpret_cast<const float4*>(sigma + p0);
    const float sgs[PP] = {sg4.x, sg4.y, sg4.z, sg4.w};
    float wts[PP][KK];
    float inv_norm[PP];
    #pragma unroll
    for (int p = 0; p < PP; ++p) {
        const float sig = sgs[p];
        const float inv2s2 = __builtin_amdgcn_rcpf(2.0f * sig * sig);
        const float hs = ceilf(2.0f * sig);          // half_step
        const float q  = __expf(-inv2s2);            // q = exp(-1/(2s^2))
        const float q2 = q * q;
        float wp = 1.0f;   // gated w_{i-1}
        float tq = q;      // q^(2i-1)
        float norm = 1.0f;
        #pragma unroll
        for (int i = 1; i <= KK; ++i) {
            float wi = wp * tq;                      // q^(i^2) until gated
            tq *= q2;
            wi = ((float)i <= hs) ? wi : 0.0f;       // half_step gate
            wts[p][i - 1] = wi;
            norm += 2.0f * wi;
            wp = wi;
        }
        inv_norm[p] = __builtin_amdgcn_rcpf(norm);   // norm >= 1 (center tap)
    }

    const int  base     = w0 - 12;                   // window start col
    const bool interior = (w0 >= 12) && (w0 <= WW - 16);

    #pragma unroll
    for (int c = 0; c < CC; ++c) {
        const float* __restrict__ rc = x + c * (HH * WW) + h * WW;
        float v[28];                                 // cols [w0-12, w0+15]
        if (interior) {                              // waves 0-2: uniform skip
            const float* __restrict__ bp = rc + base;   // 16B aligned
            #pragma unroll
            for (int k = 0; k < 7; ++k) {
                const float4 lv = *reinterpret_cast<const float4*>(bp + 4 * k);
                v[4*k+0] = lv.x; v[4*k+1] = lv.y;
                v[4*k+2] = lv.z; v[4*k+3] = lv.w;
            }
        } else {                                     // only last wave per row
            #pragma unroll
            for (int k = 0; k < 7; ++k) {
                const int bk = base + 4 * k;         // bk % 4 == 0
                int bkc = bk < 0 ? 0 : bk;
                bkc = bkc > (WW - 4) ? (WW - 4) : bkc;
                float4 lv = *reinterpret_cast<const float4*>(rc + bkc);
                if (k < 3) {                         // fully-left-clamped fix
                    const bool cl = bk < 0;          // lv.x == rc[0]
                    lv.y = cl ? lv.x : lv.y;
                    lv.z = cl ? lv.x : lv.z;
                    lv.w = cl ? lv.x : lv.w;
                }
                if (k > 3) {                         // fully-right-clamped fix
                    const bool cr = bk > (WW - 4);   // lv.w == rc[1023]
                    lv.x = cr ? lv.w : lv.x;
                    lv.y = cr ? lv.w : lv.y;
                    lv.z = cr ? lv.w : lv.z;
                }
                v[4*k+0] = lv.x; v[4*k+1] = lv.y;
                v[4*k+2] = lv.z; v[4*k+3] = lv.w;
            }
        }

        float4 res;
        float* rp = reinterpret_cast<float*>(&res);
        #pragma unroll
        for (int p = 0; p < PP; ++p) {
            const int o = 12 + p;                    // center index in window
            float acc = v[o];                        // center weight == 1
            #pragma unroll
            for (int i = 1; i <= KK; ++i)
                acc += wts[p][i - 1] * (v[o - i] + v[o + i]);
            rp[p] = acc * inv_norm[p];
        }
        *reinterpret_cast<float4*>(out + c * (HH * WW) + p0) = res;
    }
}

extern "C" void kernel_launch(void* const* d_in, const int* in_sizes, int n_in,
                              void* d_out, int out_size, void* d_ws, size_t ws_size,
                              hipStream_t stream) {
    const float* x = (const float*)d_in[0];
    const float* sigma = (const float*)d_in[1];
    float* out = (float*)d_out;

    const int n_threads = (HH * WW) / PP;   // 262144
    const int block = 256;
    const int grid = n_threads / block;     // 1024
    gauss1d_kernel<<<grid, block, 0, stream>>>(x, sigma, out);
}